// Round 1
// baseline (264.145 us; speedup 1.0000x reference)
//
#include <hip/hip_runtime.h>
#include <math.h>

#define BATCH 16
#define SEQ   720
#define ENC   321
#define NORD  64
#define PRED  720
#define NPAIR (BATCH*ENC)   // 5136

// workspace layout (float offsets)
#define WS_MEAN   0
#define WS_RSTD   (WS_MEAN + NPAIR)        // 5136
#define WS_STDEV  (WS_RSTD + NPAIR)        // 10272
#define WS_KT     (WS_STDEV + NPAIR)       // 15408  (720x64, t-major: K[t][m] = (A^(719-t) B)[m])
#define WS_EW     (WS_KT + PRED*NORD)      // 61488  (720x64: EW[t'][m] = sum_n eval[t'][n] W[n][m])
#define WS_EVB    (WS_EW + PRED*NORD)      // 107568 (720: eval[t']·b_mlp)
#define WS_C      (WS_EVB + PRED)          // 108288 (5136x64: c_final per pair)

#define NSTATS 96     // 16 b * 6 e-tiles(64)
#define NEWB   12     // EW blocks (60 t' rows each)

// ---------------- Kernel 1: stats + EW + Krylov build (fused) ----------------
__global__ __launch_bounds__(1024) void k1(const float* __restrict__ x,
        const float* __restrict__ A, const float* __restrict__ Bv,
        const float* __restrict__ evalm, const float* __restrict__ W,
        const float* __restrict__ bm, float* __restrict__ ws)
{
    extern __shared__ float sm[];
    const int tid  = threadIdx.x;
    const int lane = tid & 63;
    const int wv   = tid >> 6;       // wave id 0..15
    const int bid  = blockIdx.x;

    if (bid < NSTATS) {
        // -------- RevIN stats for 64 e's of one batch --------
        const int b = bid / 6, et = bid % 6;
        const int e = et*64 + lane;
        const bool valid = e < ENC;
        float sum = 0.f, ss = 0.f;
        if (valid) {
            const float* xp = x + (size_t)b*SEQ*ENC + e;
            for (int t = wv; t < SEQ; t += 16) {
                float v = xp[(size_t)t*ENC];
                sum += v; ss += v*v;
            }
        }
        float* r1 = sm; float* r2 = sm + 1024;
        r1[wv*64+lane] = sum; r2[wv*64+lane] = ss;
        __syncthreads();
        if (wv == 0 && valid) {
            float s = 0.f, q = 0.f;
            #pragma unroll
            for (int k = 0; k < 16; k++) { s += r1[k*64+lane]; q += r2[k*64+lane]; }
            float mean = s * (1.0f/SEQ);
            float var  = q * (1.0f/SEQ) - mean*mean;
            float sd   = sqrtf(var + 1e-5f);
            int p = b*ENC + e;
            ws[WS_MEAN  + p] = mean;
            ws[WS_STDEV + p] = sd;
            ws[WS_RSTD  + p] = 1.0f / sd;
        }
        // zero the C accumulator tile for this (b, e-range)
        float* C = ws + WS_C;
        for (int idx = tid; idx < 64*64; idx += 1024) {
            int el = idx >> 6, m = idx & 63;
            int ee = et*64 + el;
            if (ee < ENC) C[(size_t)(b*ENC + ee)*64 + m] = 0.f;
        }
    } else if (bid < NSTATS + NEWB) {
        // -------- EW = eval @ W  (fold MLP into eval side), evb = eval @ b --------
        const int r = bid - NSTATS;
        for (int idx = tid; idx < 64*64; idx += 1024) {
            int n = idx >> 6, m = idx & 63;
            sm[n*65 + m] = W[idx];
        }
        __syncthreads();
        float bv = bm[lane];
        #pragma unroll
        for (int k = 0; k < 4; k++) {
            int row = wv + k*16;
            if (row < 60) {
                int tp = r*60 + row;
                const float* ev = evalm + (size_t)tp*64;
                float acc = 0.f;
                #pragma unroll
                for (int kk = 0; kk < 16; kk++) {
                    float4 e4 = *(const float4*)&ev[4*kk];
                    acc += e4.x*sm[(4*kk+0)*65+lane] + e4.y*sm[(4*kk+1)*65+lane]
                         + e4.z*sm[(4*kk+2)*65+lane] + e4.w*sm[(4*kk+3)*65+lane];
                }
                ws[WS_EW + (size_t)tp*64 + lane] = acc;
                float pv = ev[lane] * bv;
                #pragma unroll
                for (int o = 32; o > 0; o >>= 1) pv += __shfl_down(pv, o);
                if (lane == 0) ws[WS_EVB + tp] = pv;
            }
        }
    } else {
        // -------- Krylov build: K[j] = A^j B by doubling; store t-major at 719-j --------
        float* Kl  = sm;                    // [256][64] rows j=0..255 (only these are ever re-read)
        float* Ap  = sm + 256*64;           // [64][68]  A^m
        float* ApT = Ap + 64*68;            // [64][68]  (A^m)^T
        float* Kt  = ws + WS_KT;
        for (int idx = tid; idx < 64*64; idx += 1024) {
            int n = idx >> 6, m = idx & 63;
            float v = A[idx];
            Ap[n*68+m] = v; ApT[m*68+n] = v;
        }
        if (tid < 64) {
            float bv = Bv[tid];
            Kl[tid] = bv;
            Kt[(size_t)719*64 + tid] = bv;
        }
        __syncthreads();
        float ar[64];                        // register cache: row `lane` of A^m
        #pragma unroll
        for (int k = 0; k < 16; k++) {
            float4 v = *(const float4*)&Ap[lane*68 + 4*k];
            ar[4*k]=v.x; ar[4*k+1]=v.y; ar[4*k+2]=v.z; ar[4*k+3]=v.w;
        }
        int m = 1;
        while (m < 720) {
            const int hi = (2*m < 720) ? 2*m : 720;
            // expand rows m..hi-1:  K[j2] = A^m @ K[j2-m]
            for (int j2 = m + wv; j2 < hi; j2 += 16) {
                const float* src = &Kl[(j2 - m)*64];
                float acc = 0.f;
                #pragma unroll
                for (int k = 0; k < 16; k++) {
                    float4 s = *(const float4*)&src[4*k];  // wave-uniform broadcast
                    acc += ar[4*k]*s.x + ar[4*k+1]*s.y + ar[4*k+2]*s.z + ar[4*k+3]*s.w;
                }
                if (j2 < 256) Kl[j2*64 + lane] = acc;
                Kt[(size_t)(719 - j2)*64 + lane] = acc;
            }
            const bool sq = (hi < 720);
            float nacc[4];
            if (sq) {
                // Anew[lane][c] = (A^m @ col_c(A^m))[lane], col from ApT row c
                #pragma unroll
                for (int q = 0; q < 4; q++) {
                    int c = wv*4 + q;
                    const float* src = &ApT[c*68];
                    float acc = 0.f;
                    #pragma unroll
                    for (int k = 0; k < 16; k++) {
                        float4 s = *(const float4*)&src[4*k];
                        acc += ar[4*k]*s.x + ar[4*k+1]*s.y + ar[4*k+2]*s.z + ar[4*k+3]*s.w;
                    }
                    nacc[q] = acc;
                }
            }
            __syncthreads();
            if (sq) {
                #pragma unroll
                for (int q = 0; q < 4; q++) {
                    int c = wv*4 + q;
                    Ap[lane*68 + c]  = nacc[q];
                    ApT[c*68 + lane] = nacc[q];
                }
            }
            __syncthreads();
            if (sq) {
                #pragma unroll
                for (int k = 0; k < 16; k++) {
                    float4 v = *(const float4*)&Ap[lane*68 + 4*k];
                    ar[4*k]=v.x; ar[4*k+1]=v.y; ar[4*k+2]=v.z; ar[4*k+3]=v.w;
                }
            }
            m = hi;
        }
    }
}

// ---------------- Kernel 2: C[p][m] += sum_t f[p][t] * K[t][m] ----------------
// grid 16b x 3 e-tiles(128) x 5 t-splits(144); 256 thr; atomicAdd into zeroed C.
__global__ __launch_bounds__(256) void k2(const float* __restrict__ x,
        const float* __restrict__ aw, const float* __restrict__ ab,
        float* __restrict__ ws)
{
    __shared__ float Ktile[16*64];
    const int tid = threadIdx.x;
    const int bid = blockIdx.x;
    const int b  = bid / 15;
    const int r  = bid % 15;
    const int et = r / 5, tsp = r % 5;
    const int e0 = et*128, t0 = tsp*144;
    const int eq = tid & 31, mq = tid >> 5;
    const int ebase = e0 + eq*4;
    const int mbase = mq*8;

    float scale[4], shift[4];
    #pragma unroll
    for (int j = 0; j < 4; j++) {
        int e = ebase + j;
        if (e < ENC) {
            int p = b*ENC + e;
            float rs = ws[WS_RSTD + p];
            float mn = ws[WS_MEAN + p];
            float a  = aw[e];
            scale[j] = rs * a;
            shift[j] = ab[e] - mn * rs * a;
        } else { scale[j] = 0.f; shift[j] = 0.f; }
    }
    float acc[4][8];
    #pragma unroll
    for (int j = 0; j < 4; j++)
        #pragma unroll
        for (int i = 0; i < 8; i++) acc[j][i] = 0.f;

    const float* Kt = ws + WS_KT;
    for (int ch = 0; ch < 9; ch++) {
        {
            int idx = tid*4;
            int tt = idx >> 6, mm = idx & 63;
            *(float4*)&Ktile[idx] = *(const float4*)&Kt[(size_t)(t0 + ch*16 + tt)*64 + mm];
        }
        __syncthreads();
        #pragma unroll 4
        for (int tt = 0; tt < 16; tt++) {
            int t = t0 + ch*16 + tt;
            const float* xp = x + ((size_t)b*SEQ + t)*ENC;
            float f[4];
            #pragma unroll
            for (int j = 0; j < 4; j++) {
                int e = ebase + j;
                float v = (e < ENC) ? xp[e] : 0.f;
                f[j] = v*scale[j] + shift[j];
            }
            float4 k0 = *(const float4*)&Ktile[tt*64 + mbase];
            float4 k1v = *(const float4*)&Ktile[tt*64 + mbase + 4];
            float kv[8] = {k0.x,k0.y,k0.z,k0.w,k1v.x,k1v.y,k1v.z,k1v.w};
            #pragma unroll
            for (int j = 0; j < 4; j++)
                #pragma unroll
                for (int i = 0; i < 8; i++)
                    acc[j][i] += f[j]*kv[i];
        }
        __syncthreads();
    }
    float* C = ws + WS_C;
    #pragma unroll
    for (int j = 0; j < 4; j++) {
        int e = ebase + j;
        if (e < ENC) {
            size_t p = (size_t)(b*ENC + e)*64 + mbase;
            #pragma unroll
            for (int i = 0; i < 8; i++) atomicAdd(&C[p + i], acc[j][i]);
        }
    }
}

// ---------------- Kernel 3: out = C @ EW^T + evb, then denorm ----------------
// grid 16b x 12 t'-tiles(64) x 6 e-tiles(64); 256 thr.
__global__ __launch_bounds__(256) void k3(const float* __restrict__ aw,
        const float* __restrict__ ab, const float* __restrict__ ws,
        float* __restrict__ out)
{
    __shared__ float EWt[64*68];   // [m][t'] transposed, pad 68
    const int tid = threadIdx.x;
    const int bid = blockIdx.x;
    const int b   = bid / 72;
    const int r   = bid % 72;
    const int tt0 = (r / 6) * 64;
    const int e0  = (r % 6) * 64;
    const int lane = tid & 63;
    const int tq   = tid >> 6;
    {
        const float* EW = ws + WS_EW;
        #pragma unroll
        for (int i = 0; i < 16; i++) {
            int tl = tq*16 + i;
            int tp = tt0 + tl;
            float v = (tp < PRED) ? EW[(size_t)tp*64 + lane] : 0.f;
            EWt[lane*68 + tl] = v;
        }
    }
    const int e = e0 + lane;
    const bool valid = e < ENC;
    const int p = b*ENC + e;
    float creg[64];
    if (valid) {
        const float* C = ws + WS_C + (size_t)p*64;
        #pragma unroll
        for (int k = 0; k < 16; k++) {
            float4 v = *(const float4*)&C[4*k];
            creg[4*k]=v.x; creg[4*k+1]=v.y; creg[4*k+2]=v.z; creg[4*k+3]=v.w;
        }
    } else {
        #pragma unroll
        for (int k = 0; k < 64; k++) creg[k] = 0.f;
    }
    __syncthreads();
    float acc[16];
    #pragma unroll
    for (int i = 0; i < 16; i++) acc[i] = 0.f;
    #pragma unroll 8
    for (int mI = 0; mI < 64; mI++) {
        const float* wr = &EWt[mI*68 + tq*16];
        float4 w0 = *(const float4*)&wr[0];
        float4 w1 = *(const float4*)&wr[4];
        float4 w2 = *(const float4*)&wr[8];
        float4 w3 = *(const float4*)&wr[12];
        float c = creg[mI];
        acc[0]+=w0.x*c; acc[1]+=w0.y*c; acc[2]+=w0.z*c; acc[3]+=w0.w*c;
        acc[4]+=w1.x*c; acc[5]+=w1.y*c; acc[6]+=w1.z*c; acc[7]+=w1.w*c;
        acc[8]+=w2.x*c; acc[9]+=w2.y*c; acc[10]+=w2.z*c; acc[11]+=w2.w*c;
        acc[12]+=w3.x*c; acc[13]+=w3.y*c; acc[14]+=w3.z*c; acc[15]+=w3.w*c;
    }
    float mean=0.f, sd=0.f, iaw=0.f, abe=0.f;
    if (valid) {
        mean = ws[WS_MEAN + p];
        sd   = ws[WS_STDEV + p];
        iaw  = 1.0f/(aw[e] + 1e-10f);
        abe  = ab[e];
    }
    const float* evb = ws + WS_EVB;
    #pragma unroll
    for (int i = 0; i < 16; i++) {
        int tp = tt0 + tq*16 + i;
        if (valid && tp < PRED) {
            float v = (acc[i] + evb[tp] - abe) * iaw * sd + mean;
            out[((size_t)b*PRED + tp)*ENC + e] = v;
        }
    }
}

extern "C" void kernel_launch(void* const* d_in, const int* in_sizes, int n_in,
                              void* d_out, int out_size, void* d_ws, size_t ws_size,
                              hipStream_t stream)
{
    const float* x     = (const float*)d_in[0];
    const float* A     = (const float*)d_in[1];
    const float* Bv    = (const float*)d_in[2];
    const float* evalm = (const float*)d_in[3];
    const float* W     = (const float*)d_in[4];
    const float* bm    = (const float*)d_in[5];
    const float* aw    = (const float*)d_in[6];
    const float* ab    = (const float*)d_in[7];
    float* ws  = (float*)d_ws;
    float* out = (float*)d_out;

    const size_t smbytes = (size_t)(256*64 + 2*64*68) * sizeof(float); // 100352 B
    hipFuncSetAttribute((const void*)k1, hipFuncAttributeMaxDynamicSharedMemorySize, (int)smbytes);

    k1<<<NSTATS + NEWB + 1, 1024, smbytes, stream>>>(x, A, Bv, evalm, W, bm, ws);
    k2<<<240, 256, 0, stream>>>(x, aw, ab, ws);
    k3<<<1152, 256, 0, stream>>>(aw, ab, ws, out);
}